// Round 6
// baseline (178.078 us; speedup 1.0000x reference)
//
#include <hip/hip_runtime.h>

// QRNN: B=8 T=2048 C=512 U=512 W=2
// R6 = R5 gemm (unchanged, proven) + transaction-optimized tail:
//  - phaseA/C: 2 u's per thread (uint loads of bf16 pairs -> 256B/wave), 256 blocks.
//  - phaseB deleted: phaseA packs (a,bv) bf16x2 into one uint; phaseC blocks
//    compute their own <=31-step chunk prefix from the 512 KB L2-hot ab[] array.
//  - conv_x: 8 elems/thread.

#define Bn 8
#define Tn 2048
#define Cn 512
#define Un 512
#define Nn 1536
#define Kn 1024
#define Mn (Bn * Tn)
#define NC 32   // chunks per sequence
#define CL 64   // chunk length (NC*CL == Tn)

using bf16x8 = __attribute__((ext_vector_type(8))) __bf16;
using f32x4  = __attribute__((ext_vector_type(4))) float;
using us8    = __attribute__((ext_vector_type(8))) unsigned short;

__device__ __forceinline__ void async16(const void* g, void* l) {
  __builtin_amdgcn_global_load_lds((const __attribute__((address_space(1))) void*)g,
                                   (__attribute__((address_space(3))) void*)l, 16, 0, 0);
}

__device__ __forceinline__ unsigned short f2bf(float v) {
  union { float f; unsigned u; } c; c.f = v;
  unsigned u = c.u;
  return (unsigned short)((u + 0x7fffu + ((u >> 16) & 1u)) >> 16);  // RNE
}
__device__ __forceinline__ float asf(unsigned u) {
  union { unsigned u; float f; } c; c.u = u; return c.f;
}
// unpack a uint holding two bf16 (low = element u, high = element u+1)
__device__ __forceinline__ float bf_lo(unsigned w) { return asf(w << 16); }
__device__ __forceinline__ float bf_hi(unsigned w) { return asf(w & 0xffff0000u); }

__device__ __forceinline__ float fast_sigmoid(float x) {
  float e = __builtin_amdgcn_exp2f(-1.4426950408889634f * x);
  return __builtin_amdgcn_rcpf(1.0f + e);
}
__device__ __forceinline__ float fast_tanh(float x) {
  float e = __builtin_amdgcn_exp2f(-2.8853900817779268f * x);
  return 2.0f * __builtin_amdgcn_rcpf(1.0f + e) - 1.0f;
}

// ---- 1. x -> padded bf16 (8 elems/thread) -----------------------------------
__global__ __launch_bounds__(256) void conv_x(const float* __restrict__ x,
                                              unsigned short* __restrict__ xb) {
  int idx = blockIdx.x * 256 + threadIdx.x;   // over B*(T+1)*C/8
  int c8  = idx & 63;                         // C/8 = 64
  int row = idx >> 6;                         // b*(T+1)+t
  int b   = row / (Tn + 1);
  int t   = row - b * (Tn + 1);
  us8 ov;
  if (t == 0) {
    ov = (us8)0;
  } else {
    const float* src = x + (size_t)(b * Tn + t - 1) * Cn + c8 * 8;
    float4 v0 = *(const float4*)src;
    float4 v1 = *(const float4*)(src + 4);
    ov[0] = f2bf(v0.x); ov[1] = f2bf(v0.y); ov[2] = f2bf(v0.z); ov[3] = f2bf(v0.w);
    ov[4] = f2bf(v1.x); ov[5] = f2bf(v1.y); ov[6] = f2bf(v1.z); ov[7] = f2bf(v1.w);
  }
  *(us8*)(xb + (size_t)row * Cn + c8 * 8) = ov;
}

// ---- 2. kernel -> bf16 transposed [N][K] ------------------------------------
__global__ __launch_bounds__(256) void conv_k(const float* __restrict__ kern,
                                              unsigned short* __restrict__ kT) {
  __shared__ float tile[32][33];
  int kb = blockIdx.x, nb = blockIdx.y;       // grid (32, 48)
  int tx = threadIdx.x & 31, ty = threadIdx.x >> 5;
#pragma unroll
  for (int i = 0; i < 4; i++)
    tile[ty + i * 8][tx] = kern[(size_t)(kb * 32 + ty + i * 8) * Nn + nb * 32 + tx];
  __syncthreads();
#pragma unroll
  for (int i = 0; i < 4; i++) {
    int n = nb * 32 + ty + i * 8;
    int k = kb * 32 + tx;
    kT[(size_t)n * Kn + k] = f2bf(tile[tx][ty + i * 8]);
  }
}

// ---- 3. MFMA GEMM + activation epilogue (R5, unchanged) ---------------------
// Block tile 128x128, BK=64, 4 waves (2x2 of 64x64).
// LDS: As/Bs [128 rows][64 shorts], frag [row][kq] stored at 16B-col kq^(row&7).
__global__ __launch_bounds__(256) void gemm_gates(const unsigned short* __restrict__ xb,
                                                  const unsigned short* __restrict__ kT,
                                                  const float* __restrict__ bias,
                                                  unsigned short* __restrict__ gates) {
  __shared__ unsigned short As[128 * 64];   // 16 KB
  __shared__ unsigned short Bs[128 * 64];   // 16 KB
  const int tid = threadIdx.x;
  const int m0 = blockIdx.x * 128;
  const int n0 = blockIdx.y * 128;
  const int batch = m0 / Tn;                // tiles never cross batch
  const int lane = tid & 63;
  const int w = tid >> 6, wr = w >> 1, wc = w & 1;

  const int srow = (w << 3) + (lane >> 3);        // + j*32 per call
  const int skq  = (lane & 7) ^ (lane >> 3);      // frag index this lane fetches
  const unsigned short* aStage = xb + (size_t)(m0 + batch + srow) * Cn + (skq << 3);
  const unsigned short* bStage = kT + (size_t)(n0 + srow) * Kn + (skq << 3);

  f32x4 zero = {0.f, 0.f, 0.f, 0.f};
  f32x4 acc[4][4];
#pragma unroll
  for (int i = 0; i < 4; i++)
#pragma unroll
    for (int j = 0; j < 4; j++) acc[i][j] = zero;

  const int rA0 = wr * 64 + (lane & 15);    // frag row base for A reads
  const int rB0 = wc * 64 + (lane & 15);
  const int swz = lane & 7;                 // row&7 for frag reads

  for (int k0 = 0; k0 < Kn; k0 += 64) {
#pragma unroll
    for (int j = 0; j < 4; j++) {
      async16(aStage + (size_t)(j << 5) * Cn + k0, &As[(j * 256 + tid) * 8]);
      async16(bStage + (size_t)(j << 5) * Kn + k0, &Bs[(j * 256 + tid) * 8]);
    }
    __builtin_amdgcn_s_waitcnt(0);
    __syncthreads();

#pragma unroll
    for (int ks = 0; ks < 2; ks++) {
      const int col = (((ks << 2) + (lane >> 4)) ^ swz) << 3;  // swizzled 16B col (shorts)
      bf16x8 af[4], bf[4];
#pragma unroll
      for (int i = 0; i < 4; i++) {
        af[i] = *(const bf16x8*)&As[(rA0 + i * 16) * 64 + col];
        bf[i] = *(const bf16x8*)&Bs[(rB0 + i * 16) * 64 + col];
      }
#pragma unroll
      for (int i = 0; i < 4; i++)
#pragma unroll
        for (int j = 0; j < 4; j++)
          acc[i][j] = __builtin_amdgcn_mfma_f32_16x16x32_bf16(af[i], bf[j], acc[i][j], 0, 0, 0);
    }
    __syncthreads();
  }

  // epilogue: C/D layout col=lane&15 (N), row=(lane>>4)*4+r (M); store bf16
  const int region = blockIdx.y >> 2;       // 0=z(tanh) 1=f(sig) 2=o(sig)
  const int rowB = wr * 64 + (lane >> 4) * 4;
  const int colB = wc * 64 + (lane & 15);
#pragma unroll
  for (int i = 0; i < 4; i++)
#pragma unroll
    for (int j = 0; j < 4; j++)
#pragma unroll
      for (int r = 0; r < 4; r++) {
        int mm = m0 + rowB + i * 16 + r;
        int nn = n0 + colB + j * 16;
        float g = acc[i][j][r] + bias[nn];
        float a = (region == 0) ? fast_tanh(g) : fast_sigmoid(g);
        gates[(size_t)mm * Nn + nn] = f2bf(a);
      }
}

// ---- 4. per-chunk affine; pack (a,bv) as bf16x2 in one uint -----------------
// grid 256 (one chunk per block), 256 threads, 2 u per thread.
__global__ __launch_bounds__(256) void scan_phaseA(const unsigned short* __restrict__ gates,
                                                   unsigned int* __restrict__ ab) {
  int chunk = blockIdx.x;
  int b = chunk >> 5, c = chunk & (NC - 1);
  int u2 = threadIdx.x * 2;
  const unsigned short* gp = gates + (size_t)(b * Tn + c * CL) * Nn;
  float a0 = 1.f, a1 = 1.f, bv0 = 0.f, bv1 = 0.f;
#pragma unroll 8
  for (int t = 0; t < CL; t++) {
    unsigned zz = *(const unsigned*)(gp + u2);
    unsigned ff = *(const unsigned*)(gp + Un + u2);
    float z0 = bf_lo(zz), z1 = bf_hi(zz);
    float f0 = bf_lo(ff), f1 = bf_hi(ff);
    a0 *= f0; a1 *= f1;
    bv0 = f0 * bv0 + (1.0f - f0) * z0;
    bv1 = f1 * bv1 + (1.0f - f1) * z1;
    gp += Nn;
  }
  uint2 w;
  w.x = ((unsigned)f2bf(a0) << 16) | f2bf(bv0);
  w.y = ((unsigned)f2bf(a1) << 16) | f2bf(bv1);
  *(uint2*)(ab + (size_t)chunk * Un + u2) = w;
}

// ---- 5. replay chunk; prefix computed in-block from ab[] --------------------
// grid 256 (one chunk per block), 256 threads, 2 u per thread.
__global__ __launch_bounds__(256) void scan_phaseC(const unsigned short* __restrict__ gates,
                                                   const unsigned int* __restrict__ ab,
                                                   const float* __restrict__ init,
                                                   float* __restrict__ out) {
  int chunk = blockIdx.x;
  int b = chunk >> 5, c = chunk & (NC - 1);
  int u2 = threadIdx.x * 2;
  float h0 = init[u2], h1 = init[u2 + 1];
  // prefix over earlier chunks of this batch (ab[] is 512 KB, L2-hot)
  for (int cp = 0; cp < c; cp++) {
    uint2 w = *(const uint2*)(ab + (size_t)(b * NC + cp) * Un + u2);
    h0 = asf(w.x & 0xffff0000u) * h0 + bf_lo(w.x);
    h1 = asf(w.y & 0xffff0000u) * h1 + bf_lo(w.y);
  }
  const unsigned short* gp = gates + (size_t)(b * Tn + c * CL) * Nn;
  float* op = out + (size_t)(b * Tn + c * CL) * Un;
#pragma unroll 8
  for (int t = 0; t < CL; t++) {
    unsigned zz = *(const unsigned*)(gp + u2);
    unsigned ff = *(const unsigned*)(gp + Un + u2);
    unsigned oo = *(const unsigned*)(gp + 2 * Un + u2);
    float z0 = bf_lo(zz), z1 = bf_hi(zz);
    float f0 = bf_lo(ff), f1 = bf_hi(ff);
    float o0 = bf_lo(oo), o1 = bf_hi(oo);
    h0 = f0 * h0 + (1.0f - f0) * z0;
    h1 = f1 * h1 + (1.0f - f1) * z1;
    float2 ov; ov.x = h0 * o0; ov.y = h1 * o1;
    *(float2*)(op + u2) = ov;
    gp += Nn;
    op += Un;
  }
}

extern "C" void kernel_launch(void* const* d_in, const int* in_sizes, int n_in,
                              void* d_out, int out_size, void* d_ws, size_t ws_size,
                              hipStream_t stream) {
  const float* x    = (const float*)d_in[0];  // [8,2048,512]
  const float* kern = (const float*)d_in[1];  // [2,512,1536]
  const float* bias = (const float*)d_in[2];  // [1536]
  const float* init = (const float*)d_in[3];  // [1,512]
  float* out = (float*)d_out;                 // [8,2048,512]

  char* ws = (char*)d_ws;
  unsigned short* xb = (unsigned short*)ws;                      // 16.8 MB
  size_t off = (size_t)Bn * (Tn + 1) * Cn * 2;
  unsigned short* kT = (unsigned short*)(ws + off);              // 3.1 MB
  off += (size_t)Nn * Kn * 2;
  unsigned short* gates = (unsigned short*)(ws + off);           // 50.3 MB (bf16)
  off += (size_t)Mn * Nn * 2;
  unsigned int* ab = (unsigned int*)(ws + off);                  // 512 KB

  conv_x<<<(Bn * (Tn + 1) * Cn / 8) / 256, 256, 0, stream>>>(x, xb);
  conv_k<<<dim3(32, 48), 256, 0, stream>>>(kern, kT);
  gemm_gates<<<dim3(Mn / 128, Nn / 128), 256, 0, stream>>>(xb, kT, bias, gates);
  scan_phaseA<<<Bn * NC, 256, 0, stream>>>(gates, ab);
  scan_phaseC<<<Bn * NC, 256, 0, stream>>>(gates, ab, init, out);
}